// Round 13
// baseline (1610.650 us; speedup 1.0000x reference)
//
#include <hip/hip_runtime.h>
#include <hip/hip_bf16.h>

typedef unsigned short u16;
typedef unsigned int u32;
typedef unsigned long long u64;
typedef __attribute__((ext_vector_type(8))) short short8;
typedef __attribute__((ext_vector_type(4))) float floatx4;

#define I_DIM 256
#define H_DIM 1024
#define B_DIM 64
#define T_DIM 256
#define C_DIM 60
#define NWG   128
#define UPW   8      // hidden units per WG
#define BSTR  68     // pacc row stride (dwords): 16B-aligned, 2-way read aliasing

// LDS layout (bytes)
#define LDS_W_OFF    0        // 2*40*4*16 frags * 16B = 81920
#define LDS_PACC_OFF 81920    // 128 rows * 68 dw * 4B = 34816
#define LDS_BIAS_OFF 116736   // 32*4 = 128
#define LDS_CBUF_OFF 116864   // 512*4 = 2048
#define LDS_DCNT_OFF 118912   // 2 ints (parity drain counters) = 16
#define LDS_TOTAL    118928

// workspace layout (bytes)
#define WS_XSWZ   0u          // T*B*I bf16 = 8388608
#define WS_HSWZ   8388608u    // 256 slots * 64*1024 bf16 = 33554432 (never reused)
#define WS_CNT    41943040u   // 8 counters, 256B apart = 2048
#define WS_HLAST  41945088u   // 64*1024 f32 = 262144

__device__ __forceinline__ u16 f2bf(float f) {
    u32 u = __float_as_uint(f);
    u32 r = (u + 0x7fffu + ((u >> 16) & 1u)) >> 16;
    return (u16)r;
}
__device__ __forceinline__ float fsig(float x) { return 1.0f / (1.0f + __expf(-x)); }
__device__ __forceinline__ float ftanh(float x) { return 2.0f * fsig(2.0f * x) - 1.0f; }

// ---------------------------------------------------------------------------
// Pre-swizzle inputs [B][T][I] fp32 -> xswz[t] bf16 in MFMA-A-fragment layout:
// 16B unit index (per t): ((mt*8 + s)*4 + q)*16 + m  holds A[b=mt*16+m][k=s*32+q*8 .. +7]
// ---------------------------------------------------------------------------
extern "C" __global__ void prep_x(const float* __restrict__ in, u16* __restrict__ xswz) {
    int o = blockIdx.x * 256 + threadIdx.x;           // octet index, 524288 total
    int m = o & 15, q = (o >> 4) & 3, s = (o >> 6) & 7, mt = (o >> 9) & 3, t = o >> 11;
    int b = mt * 16 + m, k = s * 32 + q * 8;
    const float* src = in + ((size_t)(b * T_DIM + t)) * I_DIM + k;
    float4 v0 = *(const float4*)src;
    float4 v1 = *(const float4*)(src + 4);
    short8 val;
    val[0] = (short)f2bf(v0.x); val[1] = (short)f2bf(v0.y);
    val[2] = (short)f2bf(v0.z); val[3] = (short)f2bf(v0.w);
    val[4] = (short)f2bf(v1.x); val[5] = (short)f2bf(v1.y);
    val[6] = (short)f2bf(v1.z); val[7] = (short)f2bf(v1.w);
    *(short8*)(xswz + (size_t)o * 8) = val;
}

// ---------------------------------------------------------------------------
// Persistent LSTM scan (r13): r12 (gated cached broadcast, never-reused
// slots, fused register publish, precise gate) with DECONGESTED SYNC LINES:
//  - ONE global fetch_add per WG per step (was 4): each wave drains its own
//    h stores (vmcnt(0)), lane0 bumps a parity LDS drain counter; the 4th
//    arrival issues the single global add and resets the word (barrier-
//    ordered reuse at t+2). 4x fewer hot-line RMWs, same release instant.
//  - Poll backoff s_sleep(4) (~256cy) -> ~2.5x lower poll request rate on
//    the 8 counter lines.
// ---------------------------------------------------------------------------
extern "C" __global__ void __launch_bounds__(256, 1) lstm_scan(
    const u16* __restrict__ xswz, u16* hswz,
    const float* __restrict__ Wih, const float* __restrict__ Whh,
    const float* __restrict__ bih, const float* __restrict__ bhh,
    int* cnt8, float* hlast)
{
    extern __shared__ char lds[];
    u16*   Wlds   = (u16*)(lds + LDS_W_OFF);
    float* pacc   = (float*)(lds + LDS_PACC_OFF);
    float* bias   = (float*)(lds + LDS_BIAS_OFF);
    float* cbuf   = (float*)(lds + LDS_CBUF_OFF);
    int*   dcnt   = (int*)(lds + LDS_DCNT_OFF);

    const int j    = blockIdx.x;
    const int tid  = threadIdx.x;
    const int lane = tid & 63;
    const int w    = tid >> 6;

    // ---- stage W slice into LDS, bf16, B-swizzled (one-time):
    // unit wu = ((nt*40 + sg)*4 + q)*16 + nn  holds W[r(nt,nn)][sg*32+q*8 .. +7]
    for (int i = 0; i < 20; ++i) {
        int wu = tid + i * 256;
        int nn = wu & 15, q = (wu >> 4) & 3, rest = wu >> 6;
        int sg = rest % 40, nt = rest / 40;
        int n = nt * 16 + nn;
        int g = n >> 3, uu = n & 7;
        int r = g * H_DIM + j * UPW + uu;
        int kb = sg * 32 + q * 8;
        const float* src = (kb < I_DIM) ? (Wih + (size_t)r * I_DIM + kb)
                                        : (Whh + (size_t)r * H_DIM + (kb - I_DIM));
        short8 val;
        #pragma unroll
        for (int e = 0; e < 8; ++e) val[e] = (short)f2bf(src[e]);
        *(short8*)(Wlds + (size_t)wu * 8) = val;
    }
    if (tid < 32) {
        int n = tid, g = n >> 3, uu = n & 7;
        int r = g * H_DIM + j * UPW + uu;
        bias[n] = bih[r] + bhh[r];
    }
    for (int i = tid; i < 512; i += 256) cbuf[i] = 0.0f;
    if (tid == 0) { dcnt[0] = 0; dcnt[1] = 0; }
    __syncthreads();

    const int m16 = lane & 15, q4 = lane >> 4;
    const int pb = tid >> 2, pp = tid & 3;        // pointwise (b, dword-pair)

    for (int t = 0; t < T_DIM; ++t) {
        const u16* xbase = xswz + (size_t)t * (B_DIM * I_DIM);
        const u16* hbase = hswz + (size_t)t * (B_DIM * H_DIM);   // fresh slot

        short8 a[10][4];

        // ---- wave0: issue x loads FIRST (drain during poll), then poll gate
        if (w == 0) {
            #pragma unroll
            for (int ss = 0; ss < 8; ++ss)
                #pragma unroll
                for (int mt = 0; mt < 4; ++mt)
                    a[ss][mt] = *(const short8*)(xbase + ((((mt * 8 + ss) * 4) + q4) * 16 + m16) * 8);
            if (t > 0) {
                int target = 16 * t;              // 1 add per WG, 16 WGs/group
                const int* cp = cnt8 + (lane << 6);   // lane*256 bytes
                bool need = lane < 8;
                while (true) {
                    int v = need ? __hip_atomic_load(cp, __ATOMIC_RELAXED,
                                                     __HIP_MEMORY_SCOPE_AGENT)
                                 : 0x7fffffff;
                    if (__all(v >= target)) break;
                    __builtin_amdgcn_s_sleep(4);  // ~256cy backoff
                }
            }
        }
        __syncthreads();   // (C) gate passed: h(t) fully at L3

        // ---- h-part A-frag loads, cached (L2-shared per XCD), deep MLP
        if (w == 0) {
            #pragma unroll
            for (int ss = 8; ss < 10; ++ss) {
                const int sgh = ss - 8;
                #pragma unroll
                for (int mt = 0; mt < 4; ++mt)
                    a[ss][mt] = *(const short8*)(hbase + ((((mt * 32 + sgh) * 4) + q4) * 16 + m16) * 8);
            }
        } else {
            #pragma unroll
            for (int ss = 0; ss < 10; ++ss) {
                const int sgh = w * 10 + ss - 8;
                #pragma unroll
                for (int mt = 0; mt < 4; ++mt)
                    a[ss][mt] = *(const short8*)(hbase + ((((mt * 32 + sgh) * 4) + q4) * 16 + m16) * 8);
            }
        }

        // ---- MFMA loop (B frags from LDS — t-invariant layout, no spills)
        floatx4 acc[4][2];
        #pragma unroll
        for (int mt = 0; mt < 4; ++mt)
            #pragma unroll
            for (int nt = 0; nt < 2; ++nt)
                acc[mt][nt] = (floatx4){0.f, 0.f, 0.f, 0.f};

        #pragma unroll
        for (int ss = 0; ss < 10; ++ss) {
            int sg = w * 10 + ss;
            short8 b[2];
            #pragma unroll
            for (int nt = 0; nt < 2; ++nt)
                b[nt] = *(const short8*)(Wlds + ((((nt * 40 + sg) * 4) + q4) * 16 + m16) * 8);
            #pragma unroll
            for (int mt = 0; mt < 4; ++mt)
                #pragma unroll
                for (int nt = 0; nt < 2; ++nt)
                    acc[mt][nt] = __builtin_amdgcn_mfma_f32_16x16x32_bf16(
                        a[ss][mt], b[nt], acc[mt][nt], 0, 0, 0);
        }

        // ---- write K-partials transposed: pacc[(w*32+n)*BSTR + b], b128 stores
        #pragma unroll
        for (int mt = 0; mt < 4; ++mt)
            #pragma unroll
            for (int nt = 0; nt < 2; ++nt)
                *(floatx4*)(pacc + (w * 32 + nt * 16 + m16) * BSTR + mt * 16 + q4 * 4) =
                    acc[mt][nt];
        __syncthreads();   // (A) pacc ready

        // ---- pointwise + FUSED publish: thread (pb, pp) computes h elems
        // uu = 2*pp, 2*pp+1 for batch row pb, stores one packed dword.
        {
            float hv[2];
            #pragma unroll
            for (int e = 0; e < 2; ++e) {
                int uu = pp * 2 + e;
                float s[4];
                #pragma unroll
                for (int g = 0; g < 4; ++g) {
                    int n = g * 8 + uu;
                    float v = bias[n];
                    #pragma unroll
                    for (int ww = 0; ww < 4; ++ww) v += pacc[(ww * 32 + n) * BSTR + pb];
                    s[g] = v;
                }
                float ig = fsig(s[0]), fg = fsig(s[1]), gg = ftanh(s[2]), og = fsig(s[3]);
                float c = fg * cbuf[pb * 8 + uu] + ig * gg;
                cbuf[pb * 8 + uu] = c;
                hv[e] = og * ftanh(c);
            }
            if (t + 1 < T_DIM) {
                u32 val = (u32)f2bf(hv[0]) | ((u32)f2bf(hv[1]) << 16);
                u16* hw = hswz + (size_t)(t + 1) * (B_DIM * H_DIM);
                // 16B unit per (j,b): ((mt*32+(j>>2))*4+(j&3))*16+mm; dword pp
                u32* dst = (u32*)hw
                    + ((((pb >> 4) * 32 + (j >> 2)) * 4 + (j & 3)) * 16 + (pb & 15)) * 4 + pp;
                __hip_atomic_store(dst, val, __ATOMIC_RELAXED, __HIP_MEMORY_SCOPE_AGENT);
                // per-wave drain; 4th-arriving wave does the ONE global add
                asm volatile("s_waitcnt vmcnt(0)" ::: "memory");
                if (lane == 0) {
                    int old = __hip_atomic_fetch_add(&dcnt[t & 1], 1, __ATOMIC_RELAXED,
                                                     __HIP_MEMORY_SCOPE_WORKGROUP);
                    if (old == 3) {
                        *(volatile int*)&dcnt[t & 1] = 0;  // reuse at t+2 (barrier-ordered)
                        __hip_atomic_fetch_add(cnt8 + ((j >> 4) << 6), 1, __ATOMIC_RELAXED,
                                               __HIP_MEMORY_SCOPE_AGENT);
                    }
                }
            } else {
                hlast[pb * H_DIM + j * UPW + pp * 2]     = hv[0];
                hlast[pb * H_DIM + j * UPW + pp * 2 + 1] = hv[1];
            }
        }
        // no barrier here: next step's pacc writes happen only after
        // barrier (C), which every wave reaches after finishing pointwise(t).
    }
}

// ---------------------------------------------------------------------------
// FC + log_softmax: one wave per batch row. logits[b][c] = h.fc_w[c] + fc_b[c]
// ---------------------------------------------------------------------------
extern "C" __global__ void fc_logsoftmax(const float* __restrict__ hlast,
                                         const float* __restrict__ fcw,
                                         const float* __restrict__ fcb,
                                         float* __restrict__ out)
{
    int b = blockIdx.x, c = threadIdx.x;  // 64 threads, 1 wave
    float acc = 0.0f;
    if (c < C_DIM) {
        const float* wr = fcw + (size_t)c * H_DIM;
        const float* hr = hlast + (size_t)b * H_DIM;
        for (int k = 0; k < H_DIM; k += 4) {
            float4 hv = *(const float4*)(hr + k);
            float4 wv = *(const float4*)(wr + k);
            acc += hv.x * wv.x + hv.y * wv.y + hv.z * wv.z + hv.w * wv.w;
        }
        acc += fcb[c];
    }
    float logit = (c < C_DIM) ? acc : -1e30f;
    float mx = logit;
    #pragma unroll
    for (int off = 32; off; off >>= 1) mx = fmaxf(mx, __shfl_xor(mx, off));
    float e = (c < C_DIM) ? expf(logit - mx) : 0.0f;
    float sum = e;
    #pragma unroll
    for (int off = 32; off; off >>= 1) sum += __shfl_xor(sum, off);
    if (c < C_DIM) out[b * C_DIM + c] = logit - mx - logf(sum);
}

extern "C" void kernel_launch(void* const* d_in, const int* in_sizes, int n_in,
                              void* d_out, int out_size, void* d_ws, size_t ws_size,
                              hipStream_t stream)
{
    const float* inputs = (const float*)d_in[0];
    const float* Wih    = (const float*)d_in[1];
    const float* Whh    = (const float*)d_in[2];
    const float* bih    = (const float*)d_in[3];
    const float* bhh    = (const float*)d_in[4];
    const float* fcw    = (const float*)d_in[5];
    const float* fcb    = (const float*)d_in[6];
    float* out = (float*)d_out;

    char* ws = (char*)d_ws;
    u16*   xswz  = (u16*)(ws + WS_XSWZ);
    u16*   hswz  = (u16*)(ws + WS_HSWZ);
    int*   cnt8  = (int*)(ws + WS_CNT);
    float* hlast = (float*)(ws + WS_HLAST);

    // slot 0 = h_0 = 0; counters = 0. Kernel-boundary release makes these
    // visible to all cached readers. Slots t>=1 are written before any read
    // (precise gate), so poison is never observed.
    hipMemsetAsync(hswz, 0, B_DIM * H_DIM * sizeof(u16), stream);
    hipMemsetAsync(cnt8, 0, 2048, stream);

    prep_x<<<2048, 256, 0, stream>>>(inputs, xswz);

    (void)hipFuncSetAttribute((const void*)lstm_scan,
                              hipFuncAttributeMaxDynamicSharedMemorySize, LDS_TOTAL);
    lstm_scan<<<NWG, 256, LDS_TOTAL, stream>>>(xswz, hswz, Wih, Whh, bih, bhh,
                                               cnt8, hlast);
    fc_logsoftmax<<<B_DIM, 64, 0, stream>>>(hlast, fcw, fcb, out);
}